// Round 1
// baseline (296.397 us; speedup 1.0000x reference)
//
#include <hip/hip_runtime.h>

// One thread processes 4 rows:
//   input  4*7  = 28 floats = 112 B (16B-aligned at 112*i) -> 7 float4 loads
//   output 4*12 = 48 floats = 192 B (16B-aligned at 192*i) -> 12 float4 stores
__global__ __launch_bounds__(256) void quat_pose_kernel(
    const float* __restrict__ x, float* __restrict__ out, int nquad, int B) {
    int i = blockIdx.x * blockDim.x + threadIdx.x;
    if (i >= nquad) return;

    long long row0 = 4ll * i;

    if (row0 + 4 <= (long long)B) {
        // fast vector path
        const float4* xin = (const float4*)(x + 28ll * i);
        float4 v[7];
#pragma unroll
        for (int k = 0; k < 7; k++) v[k] = xin[k];
        const float* f = (const float*)v;

        float4 o[12];
        float* w4 = (float*)o;
#pragma unroll
        for (int r = 0; r < 4; r++) {
            const float* p = f + 7 * r;
            float q0 = p[0], q1 = p[1], q2 = p[2], q3 = p[3];
            float t0 = p[4], t1 = p[5], t2 = p[6];
            float q00 = q0 * q0, q11 = q1 * q1, q22 = q2 * q2, q33 = q3 * q3;
            float* w = w4 + 12 * r;
            w[0]  = q00 + q11 - q22 - q33;
            w[1]  = 2.0f * (q1 * q2 - q0 * q3);
            w[2]  = 2.0f * (q1 * q3 + q0 * q2);
            w[3]  = t0;
            w[4]  = 2.0f * (q1 * q2 + q0 * q3);
            w[5]  = q00 - q11 + q22 - q33;
            w[6]  = 2.0f * (q2 * q3 - q0 * q1);
            w[7]  = t1;
            w[8]  = 2.0f * (q1 * q3 - q0 * q2);
            w[9]  = 2.0f * (q2 * q3 + q0 * q1);
            w[10] = q00 - q11 - q22 + q33;
            w[11] = t2;
        }
        float4* op = (float4*)(out + 48ll * i);
#pragma unroll
        for (int k = 0; k < 12; k++) op[k] = o[k];
    } else {
        // tail: scalar per-row (B % 4 rows; B=4M is divisible by 4, kept for safety)
        for (long long r = row0; r < (long long)B; ++r) {
            const float* p = x + 7ll * r;
            float q0 = p[0], q1 = p[1], q2 = p[2], q3 = p[3];
            float t0 = p[4], t1 = p[5], t2 = p[6];
            float q00 = q0 * q0, q11 = q1 * q1, q22 = q2 * q2, q33 = q3 * q3;
            float* w = out + 12ll * r;
            w[0]  = q00 + q11 - q22 - q33;
            w[1]  = 2.0f * (q1 * q2 - q0 * q3);
            w[2]  = 2.0f * (q1 * q3 + q0 * q2);
            w[3]  = t0;
            w[4]  = 2.0f * (q1 * q2 + q0 * q3);
            w[5]  = q00 - q11 + q22 - q33;
            w[6]  = 2.0f * (q2 * q3 - q0 * q1);
            w[7]  = t1;
            w[8]  = 2.0f * (q1 * q3 - q0 * q2);
            w[9]  = 2.0f * (q2 * q3 + q0 * q1);
            w[10] = q00 - q11 - q22 + q33;
            w[11] = t2;
        }
    }
}

extern "C" void kernel_launch(void* const* d_in, const int* in_sizes, int n_in,
                              void* d_out, int out_size, void* d_ws, size_t ws_size,
                              hipStream_t stream) {
    const float* x = (const float*)d_in[0];
    float* out = (float*)d_out;
    int B = in_sizes[0] / 7;          // 4,000,000
    int nquad = (B + 3) / 4;          // threads, 4 rows each
    int block = 256;
    int grid = (nquad + block - 1) / block;
    quat_pose_kernel<<<grid, block, 0, stream>>>(x, out, nquad, B);
}

// Round 2
// 270.140 us; speedup vs baseline: 1.0972x; 1.0972x over previous
//
#include <hip/hip_runtime.h>

// B = 4,000,000 rows. One row per thread, 256 rows per block (B % 256 == 0).
// Stage global<->LDS so every global memory instruction is unit-stride float4.
//
// LDS layout:
//   s_in : 1792 floats (256 rows * 7), linear — written by coalesced float4
//          loads, read per-thread at stride 7 (coprime with 32 banks).
//   s_out: 256 rows * pitch 13 = 3328 floats — written per-thread at pitch 13
//          (coprime with 32 banks), read as float4 chunks (row pitch 13, 4-float
//          chunks at offsets 0/4/8 stay contiguous) for coalesced stores.

__global__ __launch_bounds__(256) void quat_pose_kernel(
    const float* __restrict__ x, float* __restrict__ out, int B) {
    __shared__ float s_in[1792];
    __shared__ float s_out[256 * 13];

    const int t = threadIdx.x;
    const int b = blockIdx.x;
    const long long rowBase = 256ll * b;

    // ---- stage 1: coalesced global -> LDS (448 float4 per block) ----
    const long long inF4Base = 448ll * b;          // 7*rowBase/4
    const long long totalInF4 = (7ll * B) / 4;     // B multiple of 4
    {
        const float4* xin4 = (const float4*)x;
        long long i0 = inF4Base + t;
        if (i0 < totalInF4) {
            float4 v = xin4[i0];
            ((float4*)s_in)[t] = v;
        }
        if (t < 192) {
            long long i1 = inF4Base + 256 + t;
            if (i1 < totalInF4) {
                float4 v = xin4[i1];
                ((float4*)s_in)[256 + t] = v;
            }
        }
    }
    __syncthreads();

    // ---- stage 2: compute one row per thread ----
    {
        const long long r = rowBase + t;
        if (r < (long long)B) {
            const float* p = s_in + 7 * t;
            float q0 = p[0], q1 = p[1], q2 = p[2], q3 = p[3];
            float t0 = p[4], t1 = p[5], t2 = p[6];
            float q00 = q0 * q0, q11 = q1 * q1, q22 = q2 * q2, q33 = q3 * q3;
            float* w = s_out + 13 * t;
            w[0]  = q00 + q11 - q22 - q33;
            w[1]  = 2.0f * (q1 * q2 - q0 * q3);
            w[2]  = 2.0f * (q1 * q3 + q0 * q2);
            w[3]  = t0;
            w[4]  = 2.0f * (q1 * q2 + q0 * q3);
            w[5]  = q00 - q11 + q22 - q33;
            w[6]  = 2.0f * (q2 * q3 - q0 * q1);
            w[7]  = t1;
            w[8]  = 2.0f * (q1 * q3 - q0 * q2);
            w[9]  = 2.0f * (q2 * q3 + q0 * q1);
            w[10] = q00 - q11 - q22 + q33;
            w[11] = t2;
        }
    }
    __syncthreads();

    // ---- stage 3: LDS -> coalesced global (768 float4 per block) ----
    {
        const long long outF4Base = 768ll * b;     // 12*rowBase/4
        const long long totalOutF4 = 3ll * B;      // 12*B/4
        float4* out4 = (float4*)out;
#pragma unroll
        for (int k = 0; k < 3; k++) {
            int m = t + 256 * k;                   // local float4 index, 0..767
            long long gm = outF4Base + m;
            if (gm < totalOutF4) {
                int row = m / 3;
                int off = 4 * (m % 3);
                float4 v = *(const float4*)(s_out + 13 * row + off);
                out4[gm] = v;
            }
        }
    }
}

extern "C" void kernel_launch(void* const* d_in, const int* in_sizes, int n_in,
                              void* d_out, int out_size, void* d_ws, size_t ws_size,
                              hipStream_t stream) {
    const float* x = (const float*)d_in[0];
    float* out = (float*)d_out;
    int B = in_sizes[0] / 7;                       // 4,000,000
    int grid = (B + 255) / 256;                    // 15625, exact
    quat_pose_kernel<<<grid, 256, 0, stream>>>(x, out, B);
}

// Round 4
// 258.066 us; speedup vs baseline: 1.1485x; 1.0468x over previous
//
#include <hip/hip_runtime.h>

// B = 4,000,000 rows. One row per thread, 256 rows per block.
// Stage global<->LDS so every global memory instruction is unit-stride 16B.
// Nontemporal hints on the global streams (read-once input, write-once output)
// to avoid L2 allocate churn between the three streams.
//
// LDS layout:
//   s_in : 1792 floats (256 rows * 7), linear — written by coalesced 16B
//          loads, read per-thread at stride 7 (coprime with 32 banks -> free).
//   s_out: 256 rows * pitch 13 — written per-thread at pitch 13 (coprime with
//          32 banks -> free), read back as 4-float chunks for coalesced stores.

typedef float f32x4 __attribute__((ext_vector_type(4)));

template <bool EXACT>
__global__ __launch_bounds__(256) void quat_pose_kernel(
    const float* __restrict__ x, float* __restrict__ out, int B) {
    __shared__ float s_in[1792];
    __shared__ float s_out[256 * 13];

    const int t = threadIdx.x;
    const int b = blockIdx.x;

    // ---- stage 1: coalesced global -> LDS (448 x 16B per block) ----
    const long long inF4Base = 448ll * b;
    {
        const f32x4* xin4 = (const f32x4*)x;
        if (EXACT) {
            ((f32x4*)s_in)[t] = __builtin_nontemporal_load(&xin4[inF4Base + t]);
            if (t < 192)
                ((f32x4*)s_in)[256 + t] =
                    __builtin_nontemporal_load(&xin4[inF4Base + 256 + t]);
        } else {
            const long long totalInF4 = (7ll * B) / 4;
            long long i0 = inF4Base + t;
            if (i0 < totalInF4) ((f32x4*)s_in)[t] = xin4[i0];
            long long i1 = inF4Base + 256 + t;
            if (t < 192 && i1 < totalInF4) ((f32x4*)s_in)[256 + t] = xin4[i1];
        }
    }
    __syncthreads();

    // ---- stage 2: compute one row per thread ----
    {
        const long long r = 256ll * b + t;
        if (EXACT || r < (long long)B) {
            const float* p = s_in + 7 * t;
            float q0 = p[0], q1 = p[1], q2 = p[2], q3 = p[3];
            float t0 = p[4], t1 = p[5], t2 = p[6];
            float q00 = q0 * q0, q11 = q1 * q1, q22 = q2 * q2, q33 = q3 * q3;
            float* w = s_out + 13 * t;
            w[0]  = q00 + q11 - q22 - q33;
            w[1]  = 2.0f * (q1 * q2 - q0 * q3);
            w[2]  = 2.0f * (q1 * q3 + q0 * q2);
            w[3]  = t0;
            w[4]  = 2.0f * (q1 * q2 + q0 * q3);
            w[5]  = q00 - q11 + q22 - q33;
            w[6]  = 2.0f * (q2 * q3 - q0 * q1);
            w[7]  = t1;
            w[8]  = 2.0f * (q1 * q3 - q0 * q2);
            w[9]  = 2.0f * (q2 * q3 + q0 * q1);
            w[10] = q00 - q11 - q22 + q33;
            w[11] = t2;
        }
    }
    __syncthreads();

    // ---- stage 3: LDS -> coalesced global (768 x 16B per block) ----
    {
        const long long outF4Base = 768ll * b;
        f32x4* out4 = (f32x4*)out;
#pragma unroll
        for (int k = 0; k < 3; k++) {
            int m = t + 256 * k;                   // local 16B index, 0..767
            long long gm = outF4Base + m;
            int row = m / 3;
            int off = 4 * (m % 3);
            f32x4 v;
            v.x = s_out[13 * row + off + 0];
            v.y = s_out[13 * row + off + 1];
            v.z = s_out[13 * row + off + 2];
            v.w = s_out[13 * row + off + 3];
            if (EXACT) {
                __builtin_nontemporal_store(v, &out4[gm]);
            } else {
                if (gm < 3ll * B) out4[gm] = v;
            }
        }
    }
}

extern "C" void kernel_launch(void* const* d_in, const int* in_sizes, int n_in,
                              void* d_out, int out_size, void* d_ws, size_t ws_size,
                              hipStream_t stream) {
    const float* x = (const float*)d_in[0];
    float* out = (float*)d_out;
    int B = in_sizes[0] / 7;                       // 4,000,000
    int grid = (B + 255) / 256;
    if (B % 256 == 0) {
        quat_pose_kernel<true><<<grid, 256, 0, stream>>>(x, out, B);
    } else {
        quat_pose_kernel<false><<<grid, 256, 0, stream>>>(x, out, B);
    }
}